// Round 7
// baseline (846.112 us; speedup 1.0000x reference)
//
#include <hip/hip_runtime.h>
#include <math.h>

// ForwardSumLoss (CTC forward), MI355X — single-wave streaming design.
// One block = one batch = ONE wave64. NO producers, NO barriers, NO LDS in
// the main loop. [R5/R6 lesson: the 4-wave producer/consumer structure has
// a ~2.6us FIXED cost per barrier phase, flat vs work (R5), only ~6% of
// which was the vmcnt drain (R6). 125 phases x fixed latency was the
// floor -> remove the phases.]
// Per lane: 8 (u,o) state pairs (u_P=a[2P]+a[2P-1], o_P=a[2P+1], P=8*lane+j;
// algebra verified on HW in R2). Cross-lane hop = DPP wave_shr:1 (R4).
// Weights come straight from global memory: 2 dwordx4/lane/step prefetched
// 16 steps ahead into two 8-slot register banks (all indices compile-time;
// slot reloaded immediately after consumption -> 16-step lead >> HBM
// latency, input is L3-resident anyway). exp + masking done in-wave.
// Denominator log-sum: per-step 6-stage __shfl_xor butterfly (proven
// primitive) off the serial recursion chain; rescale fold every 16 steps.

namespace {
constexpr int kB = 64;
constexpr int kT = 2000;
constexpr int kL = 400;
constexpr float kEblank = 0.36787944117144233f;   // exp(-1)
}

// lane-1 shift, pure VALU: DPP wave_shr:1 (0x138), bound_ctrl=true -> lane 0
// reads 0. Verified working in R4.
__device__ __forceinline__ float shift1(float x) {
    return __int_as_float(__builtin_amdgcn_update_dpp(
        0, __float_as_int(x), 0x138, 0xf, 0xf, true));
}

__device__ __forceinline__ float wave_sum(float x) {
    x += __shfl_xor(x, 1);
    x += __shfl_xor(x, 2);
    x += __shfl_xor(x, 4);
    x += __shfl_xor(x, 8);
    x += __shfl_xor(x, 16);
    x += __shfl_xor(x, 32);
    return x;              // uniform across the wave
}

__global__ __launch_bounds__(64, 1) void ctc_forward_kernel(
        const float* __restrict__ attn, const int* __restrict__ text_lens,
        const int* __restrict__ mel_lens, float* __restrict__ loss_ws) {
    __shared__ float su[512];

    const int b    = blockIdx.x;
    const int lane = threadIdx.x;
    const int Lb = text_lens[b];
    const int Tb = mel_lens[b];
    const int nck = (Tb + 15) / 16;

    const bool ldok = lane < 50;       // lanes 50-63 carry no states/weights
    const int  l0   = 8 * lane;        // first text index owned by this lane
    const int  qa   = 2 * lane;        // float4 column of this lane's 8 floats
    const float4* __restrict__ rp4 =
        (const float4*)(attn + (size_t)b * kT * kL);

    // two 8-step register banks; ALL indices compile-time (full unroll)
    float4 A[8][2], Bk[8][2];
    #pragma unroll
    for (int r = 0; r < 8; ++r) {
        A[r][0] = A[r][1] = Bk[r][0] = Bk[r][1] = make_float4(0.f, 0.f, 0.f, 0.f);
    }

    float u[8], o[8];
    #pragma unroll
    for (int i = 0; i < 8; ++i) { u[i] = 0.f; o[i] = 0.f; }
    double Ct = 0.0;      // applied log-rescales
    double Ld = 0.0;      // sum over t of log(se_t)
    float  ldc = 0.f;     // chunk-local float accumulator for Ld

#define LOADSLOT(BK, r, t)                                               \
    if (ldok && (t) < Tb) {                                              \
        BK[r][0] = rp4[(t) * 100 + qa];                                  \
        BK[r][1] = rp4[(t) * 100 + qa + 1];                              \
    }

// exp + denominator accumulation; declares e0..e7 in the enclosing scope
#define DENOM(XA, XB)                                                    \
    const float e0 = __expf((XA).x), e1 = __expf((XA).y);                \
    const float e2 = __expf((XA).z), e3 = __expf((XA).w);                \
    const float e4 = __expf((XB).x), e5 = __expf((XB).y);                \
    const float e6 = __expf((XB).z), e7 = __expf((XB).w);                \
    {                                                                    \
        const float s8 = ((e0 + e1) + (e2 + e3)) + ((e4 + e5) + (e6 + e7)); \
        ldc += __logf(wave_sum(ldok ? s8 : 0.f) + kEblank);              \
    }

// one recursion timestep in (u,o) form (R2-verified algebra)
#define RECUR()                                                          \
    {                                                                    \
        const float w0 = (l0 + 0 < Lb) ? e0 : 0.f;                       \
        const float w1 = (l0 + 1 < Lb) ? e1 : 0.f;                       \
        const float w2 = (l0 + 2 < Lb) ? e2 : 0.f;                       \
        const float w3 = (l0 + 3 < Lb) ? e3 : 0.f;                       \
        const float w4 = (l0 + 4 < Lb) ? e4 : 0.f;                       \
        const float w5 = (l0 + 5 < Lb) ? e5 : 0.f;                       \
        const float w6 = (l0 + 6 < Lb) ? e6 : 0.f;                       \
        const float w7 = (l0 + 7 < Lb) ? e7 : 0.f;                       \
        const float op7 = w7 * (o[7] + u[7]);                            \
        const float p   = shift1(op7);                                   \
        const float op0 = w0 * (o[0] + u[0]);                            \
        const float op1 = w1 * (o[1] + u[1]);                            \
        const float op2 = w2 * (o[2] + u[2]);                            \
        const float op3 = w3 * (o[3] + u[3]);                            \
        const float op4 = w4 * (o[4] + u[4]);                            \
        const float op5 = w5 * (o[5] + u[5]);                            \
        const float op6 = w6 * (o[6] + u[6]);                            \
        u[7] = __builtin_fmaf(kEblank, u[7], op6);                       \
        u[6] = __builtin_fmaf(kEblank, u[6], op5);                       \
        u[5] = __builtin_fmaf(kEblank, u[5], op4);                       \
        u[4] = __builtin_fmaf(kEblank, u[4], op3);                       \
        u[3] = __builtin_fmaf(kEblank, u[3], op2);                       \
        u[2] = __builtin_fmaf(kEblank, u[2], op1);                       \
        u[1] = __builtin_fmaf(kEblank, u[1], op0);                       \
        u[0] = __builtin_fmaf(kEblank, u[0], p);                         \
        o[0] = op0; o[1] = op1; o[2] = op2; o[3] = op3;                  \
        o[4] = op4; o[5] = op5; o[6] = op6; o[7] = op7;                  \
    }

// full-rate step: consume bank slot, immediately re-issue its load for the
// same row of the NEXT chunk (16-step prefetch lead)
#define FULLSTEP(BK, r, t)                                               \
    {                                                                    \
        const float4 xa = BK[r][0], xb = BK[r][1];                       \
        LOADSLOT(BK, r, (t) + 16)                                        \
        DENOM(xa, xb)                                                    \
        RECUR()                                                          \
    }

// tail step: guarded, no prefetch
#define TAILSTEP(BK, r, t)                                               \
    if ((t) < Tb) {                                                      \
        const float4 xa = BK[r][0], xb = BK[r][1];                       \
        DENOM(xa, xb)                                                    \
        RECUR()                                                          \
    }

    auto fold = [&]() {            // rescale + ledger, every 16 steps
        float ns = 0.f;
        #pragma unroll
        for (int i = 0; i < 8; ++i) ns += u[i] + o[i];
        const float tot = wave_sum(ns);          // uniform, > 0
        const float c = 1.0f / tot;
        Ct += (double)__logf(tot);
        Ld += (double)ldc;  ldc = 0.f;
        #pragma unroll
        for (int i = 0; i < 8; ++i) { u[i] *= c; o[i] *= c; }
    };

    // prologue: load rows 0..15
    #pragma unroll
    for (int r = 0; r < 8; ++r) { LOADSLOT(A,  r, r) }
    #pragma unroll
    for (int r = 0; r < 8; ++r) { LOADSLOT(Bk, r, 8 + r) }

    // ---------------- chunk 0 (row 0 = init, rows 1-15 = steps) ------------
    {
        {
            const float4 xa = A[0][0], xb = A[0][1];
            LOADSLOT(A, 0, 16)
            DENOM(xa, xb)
            if (lane == 0) { u[0] = kEblank; o[0] = e0; }   // alpha0 init
        }
        FULLSTEP(A, 1, 1)  FULLSTEP(A, 2, 2)  FULLSTEP(A, 3, 3)
        FULLSTEP(A, 4, 4)  FULLSTEP(A, 5, 5)  FULLSTEP(A, 6, 6)
        FULLSTEP(A, 7, 7)
        FULLSTEP(Bk, 0, 8)  FULLSTEP(Bk, 1, 9)  FULLSTEP(Bk, 2, 10)
        FULLSTEP(Bk, 3, 11) FULLSTEP(Bk, 4, 12) FULLSTEP(Bk, 5, 13)
        FULLSTEP(Bk, 6, 14) FULLSTEP(Bk, 7, 15)
        fold();
    }

    // ---------------- full chunks ----------------
    for (int ck = 1; ck < nck - 1; ++ck) {
        const int t0 = ck * 16;
        FULLSTEP(A, 0, t0 + 0)  FULLSTEP(A, 1, t0 + 1)
        FULLSTEP(A, 2, t0 + 2)  FULLSTEP(A, 3, t0 + 3)
        FULLSTEP(A, 4, t0 + 4)  FULLSTEP(A, 5, t0 + 5)
        FULLSTEP(A, 6, t0 + 6)  FULLSTEP(A, 7, t0 + 7)
        FULLSTEP(Bk, 0, t0 + 8)  FULLSTEP(Bk, 1, t0 + 9)
        FULLSTEP(Bk, 2, t0 + 10) FULLSTEP(Bk, 3, t0 + 11)
        FULLSTEP(Bk, 4, t0 + 12) FULLSTEP(Bk, 5, t0 + 13)
        FULLSTEP(Bk, 6, t0 + 14) FULLSTEP(Bk, 7, t0 + 15)
        fold();
    }

    // ---------------- tail chunk (guarded, no prefetch, no fold) ----------
    {
        const int t0 = (nck - 1) * 16;
        TAILSTEP(A, 0, t0 + 0)  TAILSTEP(A, 1, t0 + 1)
        TAILSTEP(A, 2, t0 + 2)  TAILSTEP(A, 3, t0 + 3)
        TAILSTEP(A, 4, t0 + 4)  TAILSTEP(A, 5, t0 + 5)
        TAILSTEP(A, 6, t0 + 6)  TAILSTEP(A, 7, t0 + 7)
        TAILSTEP(Bk, 0, t0 + 8)  TAILSTEP(Bk, 1, t0 + 9)
        TAILSTEP(Bk, 2, t0 + 10) TAILSTEP(Bk, 3, t0 + 11)
        TAILSTEP(Bk, 4, t0 + 12) TAILSTEP(Bk, 5, t0 + 13)
        TAILSTEP(Bk, 6, t0 + 14) TAILSTEP(Bk, 7, t0 + 15)
    }

    // ---------------- epilogue ----------------
    // tail of alpha = a[2Lb-1] + a[2Lb] = u at pair index Lb
    #pragma unroll
    for (int i = 0; i < 8; ++i) su[l0 + i] = u[i];
    __syncthreads();
    if (lane == 0) {
        const float tail = su[Lb];
        const double la = (double)__logf(tail) + Ct - Ld;  // -inf if tail==0
        float loss = 0.f;
        if (la > -5e29) loss = (float)(-la / (double)Lb);
        loss_ws[b] = loss;
    }

#undef LOADSLOT
#undef DENOM
#undef RECUR
#undef FULLSTEP
#undef TAILSTEP
}

__global__ void mean64_kernel(const float* __restrict__ loss_ws,
                              float* __restrict__ out) {
    float v = loss_ws[threadIdx.x];
    #pragma unroll
    for (int off = 32; off > 0; off >>= 1) v += __shfl_xor(v, off);
    if (threadIdx.x == 0) out[0] = v * (1.0f / 64.0f);
}

extern "C" void kernel_launch(void* const* d_in, const int* in_sizes, int n_in,
                              void* d_out, int out_size, void* d_ws, size_t ws_size,
                              hipStream_t stream) {
    const float* attn      = (const float*)d_in[0];
    const int*   text_lens = (const int*)d_in[1];
    const int*   mel_lens  = (const int*)d_in[2];
    float* loss_ws = (float*)d_ws;

    ctc_forward_kernel<<<kB, 64, 0, stream>>>(attn, text_lens, mel_lens, loss_ws);
    mean64_kernel<<<1, 64, 0, stream>>>(loss_ws, (float*)d_out);
}

// Round 8
// 599.389 us; speedup vs baseline: 1.4116x; 1.4116x over previous
//
#include <hip/hip_runtime.h>
#include <math.h>

// ForwardSumLoss (CTC forward), MI355X — producer/consumer WITHOUT barriers.
// [R5: phase cost ~2.6us FIXED per s_barrier phase, flat vs work.
//  R6: only ~6% of it was the vmcnt drain -> the s_barrier rendezvous
//  itself is the suspect. R7: putting exp/denominator work on the serial
//  wave costs ~380cy/step extra (butterfly+exp latency fully exposed at
//  1 wave) -> keep the work split, kill the barriers.]
// Wave 0 (consumer): R4's verified 801-state recursion (16 regs/lane, DPP
//   wave_shr:1 hop, smeared rescale reduction). Per chunk: poll a flag
//   (normally 1 LDS read), 16 steps, publish "consumed".
// Waves 1-3 (producers): each owns rows r==(wv-1) mod 3 of every chunk.
//   Per row: load 2 float4/lane from global, 8 exps, masked ds_write to
//   wbuf, UNMASKED per-row denominator via in-wave butterfly (pipelined
//   across independent rows), log -> private Ld. psum LDS eliminated.
// Sync: bounded ring depth 2 over wbuf slots. prodflag[slot][wave] = #gens
//   staged; conscnt[slot] = #gens consumed. Volatile LDS flags, s_sleep
//   polls, explicit lgkmcnt(0) before each signal. Zero main-loop barriers.

namespace {
constexpr int kB = 64;
constexpr int kT = 2000;
constexpr int kL = 400;
constexpr int kC = 16;            // timesteps per chunk
constexpr int kRow = 408;         // floats per staged row (400 + 8 guard)
constexpr float kEblank = 0.36787944117144233f;   // exp(-1)
}

// lane-1 shift, pure VALU: DPP wave_shr:1 (0x138), bound_ctrl=true -> lane 0
// reads 0. Verified on HW in R4.
__device__ __forceinline__ float shift1(float x) {
    return __int_as_float(__builtin_amdgcn_update_dpp(
        0, __float_as_int(x), 0x138, 0xf, 0xf, true));
}

__device__ __forceinline__ float wave_sum(float x) {
    x += __shfl_xor(x, 1);  x += __shfl_xor(x, 2);
    x += __shfl_xor(x, 4);  x += __shfl_xor(x, 8);
    x += __shfl_xor(x, 16); x += __shfl_xor(x, 32);
    return x;              // uniform across the wave
}

__global__ __launch_bounds__(256, 1) void ctc_forward_kernel(
        const float* __restrict__ attn, const int* __restrict__ text_lens,
        const int* __restrict__ mel_lens, float* __restrict__ loss_ws) {
    __shared__ __align__(16) float wbuf[2][kC][kRow];   // 52224 B
    __shared__ int prodflag[2][4];    // [slot][wave 1..3] = staged generation
    __shared__ int conscnt[2];        // [slot] = consumed generation
    __shared__ double sLdArr[4];

    const int b    = blockIdx.x;
    const int tid  = threadIdx.x;
    const int lane = tid & 63;
    const int wv   = tid >> 6;
    const int Lb = text_lens[b];
    const int Tb = mel_lens[b];
    const int Sb = 2 * Lb + 1;
    const int nck = (Tb + kC - 1) / kC;

    const float4* __restrict__ rp4 = (const float4*)(attn + (size_t)b * kT * kL);

    // init flags + guard zeros (words [400,408) of every row, both slots)
    if (tid < 8) prodflag[tid >> 2][tid & 3] = 0;
    if (tid < 2) conscnt[tid] = 0;
    {
        const int slot = tid >> 7, row = (tid >> 3) & 15, j = tid & 7;
        wbuf[slot][row][400 + j] = 0.f;
    }
    __syncthreads();     // the ONLY barrier before the epilogue

    if (wv == 0) {
        // ================= consumer =================
        const int gi = (lane < 50) ? lane : 50;
        float a[16];
        #pragma unroll
        for (int i = 0; i < 16; ++i) a[i] = 0.f;
        double Ct = 0.0;
        float red = 1.0f;

        auto wait_ready = [&](int ck) {
            const int s = ck & 1, tgt = (ck >> 1) + 1;
            volatile int* p1 = &prodflag[s][1];
            volatile int* p2 = &prodflag[s][2];
            volatile int* p3 = &prodflag[s][3];
            while (*p1 < tgt || *p2 < tgt || *p3 < tgt)
                __builtin_amdgcn_s_sleep(1);
            asm volatile("" ::: "memory");   // no ds_read hoists above this
        };
        auto signal_done = [&](int ck) {
            const int s = ck & 1;
            asm volatile("s_waitcnt lgkmcnt(0)" ::: "memory");
            if (lane == 0) *(volatile int*)&conscnt[s] = (ck >> 1) + 1;
        };

        auto step = [&](const float* __restrict__ wr) {
            float w[8];
            *(float4*)&w[0] = *(const float4*)(wr);
            *(float4*)&w[4] = *(const float4*)(wr + 4);
            const float p1 = shift1(a[15]);
            float n[16];
            {
                const float s = a[0] + p1;
                n[0] = kEblank * s;
                n[1] = w[0] * (a[1] + s);
            }
            #pragma unroll
            for (int j = 1; j < 8; ++j) {
                const float s = a[2 * j] + a[2 * j - 1];
                n[2 * j]     = kEblank * s;
                n[2 * j + 1] = w[j] * (a[2 * j + 1] + s);
            }
            #pragma unroll
            for (int i = 0; i < 16; ++i) a[i] = n[i];
        };
        auto fold = [&]() {
            const float tot = red;
            const float c = 1.0f / tot;
            Ct += (double)__logf(tot);
            float ns = 0.f;
            #pragma unroll
            for (int i = 0; i < 16; ++i) { a[i] *= c; ns += a[i]; }
            red = ns;
        };

        for (int ck = 0; ck < nck; ++ck) {
            wait_ready(ck);
            const float* wr = &wbuf[ck & 1][0][8 * gi];
            if (ck == 0) {
                if (lane == 0) { a[0] = kEblank; a[1] = wbuf[0][0][0]; }
                #pragma unroll
                for (int r = 1; r < kC; ++r) step(wr + r * kRow);
                fold();                               // tot==1 no-op + snapshot
            } else if (ck < nck - 1) {                // full chunk
                step(wr);             red += __shfl_xor(red, 1);
                step(wr + kRow);      red += __shfl_xor(red, 2);
                step(wr + 2 * kRow);  red += __shfl_xor(red, 4);
                step(wr + 3 * kRow);  red += __shfl_xor(red, 8);
                step(wr + 4 * kRow);  red += __shfl_xor(red, 16);
                step(wr + 5 * kRow);  red += __shfl_xor(red, 32);
                #pragma unroll
                for (int r = 6; r < kC; ++r) step(wr + r * kRow);
                fold();
            } else {                                  // tail chunk (guarded)
                const int t0 = ck * kC;
                for (int r = 0; r < kC; ++r) {
                    if (t0 + r >= Tb) break;
                    step(wr + r * kRow);
                }
            }
            signal_done(ck);
        }

        // dump final states for the epilogue (wbuf slot 0 is dead)
        float* afin = (float*)wbuf;
        if (lane <= 50) {
            #pragma unroll
            for (int i = 0; i < 16; ++i) afin[16 * lane + i] = a[i];
        }
        if (lane == 0) sLdArr[0] = Ct;   // stash Ct for tid==0 path
    } else {
        // ================= producers (waves 1-3) =================
        const bool hi = (lane < 36);
        double Ld = 0.0;
        float4 pE[6][2], pO[6][2];       // static banks, compile-time indexed
        #pragma unroll
        for (int i = 0; i < 6; ++i) {
            pE[i][0] = pE[i][1] = pO[i][0] = pO[i][1] =
                make_float4(0.f, 0.f, 0.f, 0.f);
        }

        auto wait_write_ok = [&](int ck) {
            const int g = ck >> 1;
            if (g == 0) return;
            const int s = ck & 1;
            volatile int* p = &conscnt[s];
            while (*p < g) __builtin_amdgcn_s_sleep(2);
            asm volatile("" ::: "memory");
        };
        auto signal_staged = [&](int ck) {
            const int s = ck & 1;
            asm volatile("s_waitcnt lgkmcnt(0)" ::: "memory");
            if (lane == 0) *(volatile int*)&prodflag[s][wv] = (ck >> 1) + 1;
        };

        auto load_chunk = [&](int ck, float4 (&bank)[6][2]) {
            const int t0 = ck * kC;
            #pragma unroll
            for (int i = 0; i < 6; ++i) {
                const int r = (wv - 1) + 3 * i;
                if (r < kC) {
                    const int t = t0 + r;
                    if (t < Tb) {
                        bank[i][0] = rp4[(size_t)t * 100 + lane];
                        if (hi) bank[i][1] = rp4[(size_t)t * 100 + 64 + lane];
                    }
                }
            }
        };
        auto store_chunk = [&](int ck, const float4 (&bank)[6][2]) {
            const int slot = ck & 1, t0 = ck * kC;
            float ldacc = 0.f;
            #pragma unroll
            for (int i = 0; i < 6; ++i) {
                const int r = (wv - 1) + 3 * i;
                if (r < kC) {
                    const int t = t0 + r;
                    if (t < Tb) {       // wave-uniform
                        const float4 x0 = bank[i][0];
                        const float e0 = __expf(x0.x), e1 = __expf(x0.y);
                        const float e2 = __expf(x0.z), e3 = __expf(x0.w);
                        float s = (e0 + e1) + (e2 + e3);
                        const int l0 = 4 * lane;
                        float4 w4;
                        w4.x = (l0 + 0 < Lb) ? e0 : 0.f;
                        w4.y = (l0 + 1 < Lb) ? e1 : 0.f;
                        w4.z = (l0 + 2 < Lb) ? e2 : 0.f;
                        w4.w = (l0 + 3 < Lb) ? e3 : 0.f;
                        *(float4*)&wbuf[slot][r][l0] = w4;
                        if (hi) {
                            const float4 x1 = bank[i][1];
                            const float e4 = __expf(x1.x), e5 = __expf(x1.y);
                            const float e6 = __expf(x1.z), e7 = __expf(x1.w);
                            s += (e4 + e5) + (e6 + e7);
                            const int m0 = 256 + 4 * lane;
                            float4 v4;
                            v4.x = (m0 + 0 < Lb) ? e4 : 0.f;
                            v4.y = (m0 + 1 < Lb) ? e5 : 0.f;
                            v4.z = (m0 + 2 < Lb) ? e6 : 0.f;
                            v4.w = (m0 + 3 < Lb) ? e7 : 0.f;
                            *(float4*)&wbuf[slot][r][m0] = v4;
                        }
                        ldacc += __logf(wave_sum(s) + kEblank);
                    }
                }
            }
            Ld += (double)ldacc;
        };

        // preamble
        load_chunk(0, pE);
        store_chunk(0, pE);
        signal_staged(0);
        load_chunk(1, pO);
        // main: static bank ping-pong, waits only on ring capacity
        for (int ck = 1; ck < nck; ck += 2) {
            load_chunk(ck + 1, pE);               // issue loads early
            wait_write_ok(ck);
            store_chunk(ck, pO);
            signal_staged(ck);
            if (ck + 1 < nck) {
                load_chunk(ck + 2, pO);
                wait_write_ok(ck + 1);
                store_chunk(ck + 1, pE);
                signal_staged(ck + 1);
            }
        }
        if (lane == 0) sLdArr[wv] = Ld;
    }

    __syncthreads();     // epilogue join (second and last barrier)
    if (tid == 0) {
        const float* afin = (const float*)wbuf;
        const float tail = afin[Sb - 2] + afin[Sb - 1];
        const double la = (double)__logf(tail) + sLdArr[0]
                          - (sLdArr[1] + sLdArr[2] + sLdArr[3]);
        float loss = 0.f;
        if (la > -5e29) loss = (float)(-la / (double)Lb);
        loss_ws[b] = loss;
    }
}

__global__ void mean64_kernel(const float* __restrict__ loss_ws,
                              float* __restrict__ out) {
    float v = loss_ws[threadIdx.x];
    #pragma unroll
    for (int off = 32; off > 0; off >>= 1) v += __shfl_xor(v, off);
    if (threadIdx.x == 0) out[0] = v * (1.0f / 64.0f);
}

extern "C" void kernel_launch(void* const* d_in, const int* in_sizes, int n_in,
                              void* d_out, int out_size, void* d_ws, size_t ws_size,
                              hipStream_t stream) {
    const float* attn      = (const float*)d_in[0];
    const int*   text_lens = (const int*)d_in[1];
    const int*   mel_lens  = (const int*)d_in[2];
    float* loss_ws = (float*)d_ws;

    ctc_forward_kernel<<<kB, 256, 0, stream>>>(attn, text_lens, mel_lens, loss_ws);
    mean64_kernel<<<1, 64, 0, stream>>>(loss_ws, (float*)d_out);
}